// Round 4
// baseline (440.931 us; speedup 1.0000x reference)
//
#include <hip/hip_runtime.h>
#include <math.h>

// Problem constants (match reference)
#define BATCH 4
#define NK    100000
#define IH    640
#define IW    472
#define GH    1280          // oversampled grid rows  = 2*IH
#define GW    944           // oversampled grid cols  = 2*IW
#define JW    6             // KB kernel width

static __device__ __forceinline__ float beta_f() {
    return (float)(M_PI * 4.410215414239989);   // pi*sqrt(19.45)
}

// Abramowitz & Stegun I0 approximation (rel err < 2e-7), x >= 0
static __device__ __forceinline__ float i0f_dev(float x) {
    if (x < 3.75f) {
        float t = x * (1.0f / 3.75f);
        t *= t;
        return 1.0f + t*(3.5156229f + t*(3.0899424f + t*(1.2067492f +
               t*(0.2659732f + t*(0.0360768f + t*0.0045813f)))));
    } else {
        float t = 3.75f / x;
        float p = 0.39894228f + t*(0.01328592f + t*(0.00225319f + t*(-0.00157565f +
                  t*(0.00916281f + t*(-0.02057706f + t*(0.02635537f +
                  t*(-0.01647633f + t*0.00392377f)))))));
        return p * expf(x) / sqrtf(x);
    }
}

// ---------------------------------------------------------------------------
// Kernel 1: apodize + centered zero-pad + ifftshift + ortho scale
// Handles batches [b0, b0+nb); grid holds nb batches (local index lb).
// ---------------------------------------------------------------------------
__global__ __launch_bounds__(256) void pad_apod_kernel(
        const float* __restrict__ ir, const float* __restrict__ ii,
        float2* __restrict__ grid, int b0, int nb)
{
    int idx = blockIdx.x * 256 + threadIdx.x;
    if (idx >= nb * GH * GW) return;
    int v  = idx % GW;
    int t  = idx / GW;
    int u  = t % GH;
    int lb = t / GH;          // local batch
    int b  = b0 + lb;

    // ifftshift: src = (dst + n/2) % n  (n even)
    int sx = u + GH / 2; if (sx >= GH) sx -= GH;
    int sy = v + GW / 2; if (sy >= GW) sy -= GW;
    // centered pad: image sits at [320,960) x [236,708)
    int i = sx - (GH - IH) / 2;
    int j = sy - (GW - IW) / 2;

    float2 val = make_float2(0.f, 0.f);
    if ((unsigned)i < (unsigned)IH && (unsigned)j < (unsigned)IW) {
        const float B2 = (float)(M_PI * M_PI * 19.45);   // BETA^2
        float xi = (float)(i - IH / 2) * (1.0f / (float)GH);
        float yj = (float)(j - IW / 2) * (1.0f / (float)GW);
        float px = (float)(M_PI * (double)JW) * xi;
        float py = (float)(M_PI * (double)JW) * yj;
        float zx = B2 - px * px;
        float zy = B2 - py * py;
        float sxr = sqrtf(zx);
        float syr = sqrtf(zy);
        float ax = (float)JW * sinhf(sxr) / sxr;
        float ay = (float)JW * sinhf(syr) / syr;
        const float SCALE = (float)(1.0 / 1099.236098591787);  // 1/sqrt(1280*944)
        float invA = SCALE / (ax * ay);
        size_t src = ((size_t)(b * IH + i)) * IW + j;
        val.x = ir[src] * invA;
        val.y = ii[src] * invA;
    }
    grid[idx] = val;
}

// ---------------------------------------------------------------------------
// Kernel 2: length-944 FFT along rows (944 = 59*16), only the 640 nonzero rows
// Two-stage CT:  A[k1][n2] = sum_n1 x[16*n1+n2] * W59^(n1*k1)
//                X[k]      = sum_n2 A[k%59][n2] * W944^(n2*k)
// ---------------------------------------------------------------------------
__global__ __launch_bounds__(256) void fft_row_kernel(float2* __restrict__ grid)
{
    __shared__ float2 buf[GW];
    __shared__ float2 A[GW];
    __shared__ float2 tw[GW];

    int blk = blockIdx.x;            // nb*IH blocks
    int lb = blk / IH;
    int ri = blk % IH;
    int u  = (ri < (GH - IH) / 2) ? ri : ri + IH;   // nonzero rows: [0,320) u [960,1280)
    float2* row = grid + ((size_t)(lb * GH + u)) * GW;
    int tid = threadIdx.x;

    for (int t = tid; t < GW; t += 256) {
        buf[t] = row[t];
        float ang = (float)(-2.0 * M_PI / (double)GW) * (float)t;
        float s, c;
        sincosf(ang, &s, &c);
        tw[t] = make_float2(c, s);
    }
    __syncthreads();

    // stage 1: 16 strided 59-point DFTs.  W59^t = tw[16*t]
    for (int o = tid; o < GW; o += 256) {
        int k1 = o >> 4;
        int n2 = o & 15;
        float re = 0.f, im = 0.f;
        int ti = 0;
        for (int n1 = 0; n1 < 59; ++n1) {
            float2 x = buf[(n1 << 4) + n2];
            float2 w = tw[ti << 4];
            re += x.x * w.x - x.y * w.y;
            im += x.x * w.y + x.y * w.x;
            ti += k1; if (ti >= 59) ti -= 59;
        }
        A[o] = make_float2(re, im);
    }
    __syncthreads();

    // stage 2: combined twiddle + 16-point DFT
    for (int k = tid; k < GW; k += 256) {
        int k1 = k % 59;
        int base = k1 << 4;
        float re = 0.f, im = 0.f;
        int ti = 0;
        for (int n2 = 0; n2 < 16; ++n2) {
            float2 x = A[base + n2];
            float2 w = tw[ti];
            re += x.x * w.x - x.y * w.y;
            im += x.x * w.y + x.y * w.x;
            ti += k; if (ti >= GW) ti -= GW;
        }
        row[k] = make_float2(re, im);
    }
}

// ---------------------------------------------------------------------------
// Kernel 3: length-1280 FFT along columns (1280 = 40*32)
// ---------------------------------------------------------------------------
__global__ __launch_bounds__(256) void fft_col_kernel(float2* __restrict__ grid)
{
    __shared__ float2 buf[GH];
    __shared__ float2 A[GH];
    __shared__ float2 tw[GH];

    int blk = blockIdx.x;            // nb*GW blocks
    int lb = blk / GW;
    int v  = blk % GW;
    float2* col = grid + (size_t)lb * GH * GW + v;
    int tid = threadIdx.x;

    for (int t = tid; t < GH; t += 256) {
        buf[t] = col[(size_t)t * GW];
        float ang = (float)(-2.0 * M_PI / (double)GH) * (float)t;
        float s, c;
        sincosf(ang, &s, &c);
        tw[t] = make_float2(c, s);
    }
    __syncthreads();

    // stage 1: 32 strided 40-point DFTs.  W40^t = tw[32*t]
    for (int o = tid; o < GH; o += 256) {
        int k1 = o >> 5;
        int n2 = o & 31;
        float re = 0.f, im = 0.f;
        int ti = 0;
        for (int n1 = 0; n1 < 40; ++n1) {
            float2 x = buf[(n1 << 5) + n2];
            float2 w = tw[ti << 5];
            re += x.x * w.x - x.y * w.y;
            im += x.x * w.y + x.y * w.x;
            ti += k1; if (ti >= 40) ti -= 40;
        }
        A[o] = make_float2(re, im);
    }
    __syncthreads();

    // stage 2
    for (int k = tid; k < GH; k += 256) {
        int k1 = k % 40;
        int base = k1 << 5;
        float re = 0.f, im = 0.f;
        int ti = 0;
        for (int n2 = 0; n2 < 32; ++n2) {
            float2 x = A[base + n2];
            float2 w = tw[ti];
            re += x.x * w.x - x.y * w.y;
            im += x.x * w.y + x.y * w.x;
            ti += k; if (ti >= GH) ti -= GH;
        }
        col[(size_t)k * GW] = make_float2(re, im);
    }
}

// ---------------------------------------------------------------------------
// Kernel 4: KB interpolation onto non-uniform points (batches [b0, b0+nb))
// write_complex=1: out is interleaved float2 (re,im) per point (out_size=2*B*NK)
// write_complex=0: out is real part only, one float per point (out_size=B*NK)
// ---------------------------------------------------------------------------
__global__ __launch_bounds__(256) void interp_kernel(
        const float* __restrict__ ktraj, const float2* __restrict__ grid,
        float* __restrict__ out, int b0, int nb, int write_complex)
{
    int idx = blockIdx.x * 256 + threadIdx.x;
    if (idx >= nb * NK) return;
    int lb = idx / NK;
    int k  = idx % NK;
    int b  = b0 + lb;

    const float BETA = beta_f();
    float t0 = ktraj[(size_t)(b * 2 + 0) * NK + k] * (float)((double)GH / (2.0 * M_PI));
    float t1 = ktraj[(size_t)(b * 2 + 1) * NK + k] * (float)((double)GW / (2.0 * M_PI));
    int base0 = (int)floorf(t0);
    int base1 = (int)floorf(t1);

    float wx[JW], wy[JW];
    int   ix[JW], iy[JW];
    #pragma unroll
    for (int j = 0; j < JW; ++j) {
        int kx = base0 + j - (JW / 2 - 1);        // offsets -2..3
        float u = t0 - (float)kx;
        float q = (2.0f * u) / (float)JW;
        float zz = 1.0f - q * q;
        wx[j] = (zz > 0.f) ? i0f_dev(BETA * sqrtf(zz)) : 0.f;
        int m = kx % GH; if (m < 0) m += GH;
        ix[j] = m;
    }
    #pragma unroll
    for (int j = 0; j < JW; ++j) {
        int ky = base1 + j - (JW / 2 - 1);
        float u = t1 - (float)ky;
        float q = (2.0f * u) / (float)JW;
        float zz = 1.0f - q * q;
        wy[j] = (zz > 0.f) ? i0f_dev(BETA * sqrtf(zz)) : 0.f;
        int m = ky % GW; if (m < 0) m += GW;
        iy[j] = m;
    }

    float accre = 0.f, accim = 0.f;
    #pragma unroll
    for (int a = 0; a < JW; ++a) {
        const float2* rowp = grid + ((size_t)(lb * GH + ix[a])) * GW;
        float wxa = wx[a];
        #pragma unroll
        for (int c = 0; c < JW; ++c) {
            float2 g = rowp[iy[c]];
            float w = wxa * wy[c];
            accre += w * g.x;
            accim += w * g.y;
        }
    }
    size_t p = (size_t)b * NK + k;
    if (write_complex) {
        ((float2*)out)[p] = make_float2(accre, accim);
    } else {
        out[p] = accre;            // real component only (out_size == B*NK)
    }
}

// ---------------------------------------------------------------------------
extern "C" void kernel_launch(void* const* d_in, const int* in_sizes, int n_in,
                              void* d_out, int out_size, void* d_ws, size_t ws_size,
                              hipStream_t stream)
{
    const float* ir = (const float*)d_in[0];   // [B,640,472,1] float32
    const float* ii = (const float*)d_in[1];   // [B,640,472,1] float32
    const float* kt = (const float*)d_in[2];   // [B,2,K] float32
    float2* grid = (float2*)d_ws;
    float*  out  = (float*)d_out;

    // out_size == 2*B*NK -> interleaved complex; out_size == B*NK -> real only
    int write_complex = (out_size >= 2 * BATCH * NK) ? 1 : 0;

    const size_t per_batch = (size_t)GH * GW * sizeof(float2);   // 9.67 MB
    int nb = 1;
    if (ws_size >= 4 * per_batch)      nb = 4;
    else if (ws_size >= 2 * per_batch) nb = 2;

    for (int b0 = 0; b0 < BATCH; b0 += nb) {
        int total = nb * GH * GW;
        pad_apod_kernel<<<(total + 255) / 256, 256, 0, stream>>>(ir, ii, grid, b0, nb);
        fft_row_kernel<<<nb * IH, 256, 0, stream>>>(grid);
        fft_col_kernel<<<nb * GW, 256, 0, stream>>>(grid);
        interp_kernel<<<(nb * NK + 255) / 256, 256, 0, stream>>>(kt, grid, out, b0, nb, write_complex);
    }
}

// Round 5
// 369.860 us; speedup vs baseline: 1.1922x; 1.1922x over previous
//
#include <hip/hip_runtime.h>
#include <math.h>

// Problem constants (match reference)
#define BATCH 4
#define NK    100000
#define IH    640
#define IW    472
#define GH    1280          // oversampled grid rows  = 2*IH   (1280 = 40*32)
#define GW    944           // oversampled grid cols  = 2*IW   (944  = 59*16)
#define JW    6             // KB kernel width

// twiddle table layout in ws (units: float2)
#define TW1280_OFF 0
#define TW944_OFF  1280
#define TW59_OFF   (1280 + 944)        // 2224
#define TW40_OFF   (TW59_OFF + 59)     // 2283
#define TW32_OFF   (TW40_OFF + 40)     // 2323
#define TW16_OFF   (TW32_OFF + 32)     // 2355
#define TW_TOTAL   (TW16_OFF + 16)     // 2371 float2 = 18968 B
#define TW_RESERVE_BYTES 32768

#define NC      4            // columns per fft_col block
#define CSTRIDE 5            // padded LDS row stride (float2) for fft_col buf

static __device__ __forceinline__ float beta_f() {
    return (float)(M_PI * 4.410215414239989);   // pi*sqrt(19.45)
}

// Abramowitz & Stegun I0 approximation (rel err < 2e-7), x >= 0
static __device__ __forceinline__ float i0f_dev(float x) {
    if (x < 3.75f) {
        float t = x * (1.0f / 3.75f);
        t *= t;
        return 1.0f + t*(3.5156229f + t*(3.0899424f + t*(1.2067492f +
               t*(0.2659732f + t*(0.0360768f + t*0.0045813f)))));
    } else {
        float t = 3.75f / x;
        float p = 0.39894228f + t*(0.01328592f + t*(0.00225319f + t*(-0.00157565f +
                  t*(0.00916281f + t*(-0.02057706f + t*(0.02635537f +
                  t*(-0.01647633f + t*0.00392377f)))))));
        return p * expf(x) / sqrtf(x);
    }
}

// ---------------------------------------------------------------------------
// Kernel 0: twiddle tables  tw[t] = exp(-2*pi*i*t/N)
// ---------------------------------------------------------------------------
__global__ __launch_bounds__(256) void twiddle_init_kernel(float2* __restrict__ tw)
{
    int tid = threadIdx.x;
    const float TWO_PI = 6.2831853071795864769f;
    for (int t = tid; t < 1280; t += 256) {
        float s, c; sincosf(-TWO_PI * ((float)t / 1280.f), &s, &c);
        tw[TW1280_OFF + t] = make_float2(c, s);
    }
    for (int t = tid; t < 944; t += 256) {
        float s, c; sincosf(-TWO_PI * ((float)t / 944.f), &s, &c);
        tw[TW944_OFF + t] = make_float2(c, s);
    }
    for (int t = tid; t < 59; t += 256) {
        float s, c; sincosf(-TWO_PI * ((float)t / 59.f), &s, &c);
        tw[TW59_OFF + t] = make_float2(c, s);
    }
    for (int t = tid; t < 40; t += 256) {
        float s, c; sincosf(-TWO_PI * ((float)t / 40.f), &s, &c);
        tw[TW40_OFF + t] = make_float2(c, s);
    }
    for (int t = tid; t < 32; t += 256) {
        float s, c; sincosf(-TWO_PI * ((float)t / 32.f), &s, &c);
        tw[TW32_OFF + t] = make_float2(c, s);
    }
    for (int t = tid; t < 16; t += 256) {
        float s, c; sincosf(-TWO_PI * ((float)t / 16.f), &s, &c);
        tw[TW16_OFF + t] = make_float2(c, s);
    }
}

// ---------------------------------------------------------------------------
// Kernel 1: apodize + centered zero-pad + ifftshift + ortho scale
// ---------------------------------------------------------------------------
__global__ __launch_bounds__(256) void pad_apod_kernel(
        const float* __restrict__ ir, const float* __restrict__ ii,
        float2* __restrict__ grid, int b0, int nb)
{
    int idx = blockIdx.x * 256 + threadIdx.x;
    if (idx >= nb * GH * GW) return;
    int v  = idx % GW;
    int t  = idx / GW;
    int u  = t % GH;
    int lb = t / GH;
    int b  = b0 + lb;

    int sx = u + GH / 2; if (sx >= GH) sx -= GH;
    int sy = v + GW / 2; if (sy >= GW) sy -= GW;
    int i = sx - (GH - IH) / 2;
    int j = sy - (GW - IW) / 2;

    float2 val = make_float2(0.f, 0.f);
    if ((unsigned)i < (unsigned)IH && (unsigned)j < (unsigned)IW) {
        const float B2 = (float)(M_PI * M_PI * 19.45);   // BETA^2
        float xi = (float)(i - IH / 2) * (1.0f / (float)GH);
        float yj = (float)(j - IW / 2) * (1.0f / (float)GW);
        float px = (float)(M_PI * (double)JW) * xi;
        float py = (float)(M_PI * (double)JW) * yj;
        float sxr = sqrtf(B2 - px * px);
        float syr = sqrtf(B2 - py * py);
        float ax = (float)JW * sinhf(sxr) / sxr;
        float ay = (float)JW * sinhf(syr) / syr;
        const float SCALE = (float)(1.0 / 1099.236098591787);  // 1/sqrt(1280*944)
        float invA = SCALE / (ax * ay);
        size_t src = ((size_t)(b * IH + i)) * IW + j;
        val.x = ir[src] * invA;
        val.y = ii[src] * invA;
    }
    grid[idx] = val;
}

// ---------------------------------------------------------------------------
// Kernel 2: length-944 row FFT (944 = 16*59), nonzero rows only.
//   u = 16*n1 + n2 (n1<59, n2<16); k = k1 + 59*k2 (k1<59, k2<16)
//   Z[n2*59+k1] = W944^{n2*k1} * sum_n1 x[16n1+n2] W59^{n1*k1}
//   X[k1+59k2]  = sum_n2 Z[n2*59+k1] W16^{n2*k2}
// All lane-varying LDS indices are stride-1 (conflict-free); twiddle
// recurrences stay in registers.
// ---------------------------------------------------------------------------
__global__ __launch_bounds__(256) void fft_row_kernel(
        float2* __restrict__ grid, const float2* __restrict__ twg)
{
    __shared__ float2 buf[GW];
    __shared__ float2 Z[GW];
    __shared__ float2 tw944[GW];
    __shared__ float2 tw59[59];
    __shared__ float2 tw16[16];

    int blk = blockIdx.x;            // nb*IH blocks
    int lb = blk / IH;
    int ri = blk % IH;
    int u  = (ri < (GH - IH) / 2) ? ri : ri + IH;
    float2* row = grid + ((size_t)(lb * GH + u)) * GW;
    int tid = threadIdx.x;

    for (int t = tid; t < GW; t += 256) { buf[t] = row[t]; tw944[t] = twg[TW944_OFF + t]; }
    if (tid < 59) tw59[tid] = twg[TW59_OFF + tid];
    if (tid < 16) tw16[tid] = twg[TW16_OFF + tid];
    __syncthreads();

    // stage 1
    for (int o = tid; o < GW; o += 256) {
        int k1 = o % 59;
        int n2 = o / 59;
        float2 w0 = tw59[k1];
        float wr = 1.f, wi = 0.f, re = 0.f, im = 0.f;
        for (int n1 = 0; n1 < 59; ++n1) {
            float2 x = buf[(n1 << 4) + n2];          // broadcast across lanes
            re += x.x * wr - x.y * wi;
            im += x.x * wi + x.y * wr;
            float nwr = wr * w0.x - wi * w0.y;
            wi = wr * w0.y + wi * w0.x;
            wr = nwr;
        }
        float2 tp = tw944[(n2 * k1) % GW];
        Z[o] = make_float2(re * tp.x - im * tp.y, re * tp.y + im * tp.x);
    }
    __syncthreads();

    // stage 2
    for (int m = tid; m < GW; m += 256) {
        int k1 = m % 59;
        int k2 = m / 59;
        float2 w0 = tw16[k2];
        float wr = 1.f, wi = 0.f, re = 0.f, im = 0.f;
        for (int n2 = 0; n2 < 16; ++n2) {
            float2 z = Z[n2 * 59 + k1];              // lane stride 1 -> 2-way max
            re += z.x * wr - z.y * wi;
            im += z.x * wi + z.y * wr;
            float nwr = wr * w0.x - wi * w0.y;
            wi = wr * w0.y + wi * w0.x;
            wr = nwr;
        }
        row[m] = make_float2(re, im);
    }
}

// ---------------------------------------------------------------------------
// Kernel 3: length-1280 column FFT (1280 = 32*40), 4 columns per block.
//   u = 32*n1 + n2 (n1<40, n2<32); k = k1 + 40*k2 (k1<40, k2<32)
//   Z[n2*40+k1] = W1280^{n2*k1} * sum_n1 x[32n1+n2] W40^{n1*k1}
//   X[k1+40k2]  = sum_n2 Z[n2*40+k1] W32^{n2*k2}
// buf layout [u][c] with padded stride 5 -> conflict-free; global access is
// 32B-contiguous x 4 columns per row (quarter-line utilization at worst,
// adjacent blocks cover the rest of each line).
// ---------------------------------------------------------------------------
__global__ __launch_bounds__(256) void fft_col_kernel(
        float2* __restrict__ grid, const float2* __restrict__ twg)
{
    __shared__ float2 buf[GH * CSTRIDE];   // 51200 B
    __shared__ float2 tw1280[GH];          // 10240 B
    __shared__ float2 tw40[40];
    __shared__ float2 tw32[32];

    int blk = blockIdx.x;                  // nb * 236
    int lb = blk / (GW / NC);
    int vb = blk % (GW / NC);
    float2* base = grid + (size_t)lb * GH * GW + vb * NC;
    int tid = threadIdx.x;

    #pragma unroll
    for (int it = 0; it < GH * NC / 256; ++it) {     // 20 iters
        int item = it * 256 + tid;
        int c = item & (NC - 1);
        int u = item >> 2;
        buf[u * CSTRIDE + c] = base[(size_t)u * GW + c];
    }
    for (int t = tid; t < GH; t += 256) tw1280[t] = twg[TW1280_OFF + t];
    if (tid < 40) tw40[tid] = twg[TW40_OFF + tid];
    if (tid < 32) tw32[tid] = twg[TW32_OFF + tid];
    __syncthreads();

    // stage 1 -> registers
    float2 z[20];
    #pragma unroll
    for (int it = 0; it < 20; ++it) {
        int item = it * 256 + tid;
        int c = item & 3;
        int o = item >> 2;
        int k1 = o % 40;
        int n2 = o / 40;
        float2 w0 = tw40[k1];
        float wr = 1.f, wi = 0.f, re = 0.f, im = 0.f;
        for (int n1 = 0; n1 < 40; ++n1) {
            float2 x = buf[((n1 << 5) + n2) * CSTRIDE + c];   // broadcast
            re += x.x * wr - x.y * wi;
            im += x.x * wi + x.y * wr;
            float nwr = wr * w0.x - wi * w0.y;
            wi = wr * w0.y + wi * w0.x;
            wr = nwr;
        }
        float2 tp = tw1280[(n2 * k1) % GH];
        z[it] = make_float2(re * tp.x - im * tp.y, re * tp.y + im * tp.x);
    }
    __syncthreads();
    #pragma unroll
    for (int it = 0; it < 20; ++it) {
        int item = it * 256 + tid;
        int c = item & 3;
        int o = item >> 2;
        buf[o * CSTRIDE + c] = z[it];
    }
    __syncthreads();

    // stage 2 -> global
    #pragma unroll
    for (int it = 0; it < 20; ++it) {
        int item = it * 256 + tid;
        int c = item & 3;
        int m = item >> 2;
        int k1 = m % 40;
        int k2 = m / 40;
        float2 w0 = tw32[k2];
        float wr = 1.f, wi = 0.f, re = 0.f, im = 0.f;
        for (int n2 = 0; n2 < 32; ++n2) {
            float2 zz = buf[(n2 * 40 + k1) * CSTRIDE + c];    // <=2-way
            re += zz.x * wr - zz.y * wi;
            im += zz.x * wi + zz.y * wr;
            float nwr = wr * w0.x - wi * w0.y;
            wi = wr * w0.y + wi * w0.x;
            wr = nwr;
        }
        base[(size_t)m * GW + c] = make_float2(re, im);
    }
}

// ---------------------------------------------------------------------------
// Kernel 4: KB interpolation onto non-uniform points
// ---------------------------------------------------------------------------
__global__ __launch_bounds__(256) void interp_kernel(
        const float* __restrict__ ktraj, const float2* __restrict__ grid,
        float* __restrict__ out, int b0, int nb, int write_complex)
{
    int idx = blockIdx.x * 256 + threadIdx.x;
    if (idx >= nb * NK) return;
    int lb = idx / NK;
    int k  = idx % NK;
    int b  = b0 + lb;

    const float BETA = beta_f();
    float t0 = ktraj[(size_t)(b * 2 + 0) * NK + k] * (float)((double)GH / (2.0 * M_PI));
    float t1 = ktraj[(size_t)(b * 2 + 1) * NK + k] * (float)((double)GW / (2.0 * M_PI));
    int base0 = (int)floorf(t0);
    int base1 = (int)floorf(t1);

    float wx[JW], wy[JW];
    int   ix[JW], iy[JW];
    #pragma unroll
    for (int j = 0; j < JW; ++j) {
        int kx = base0 + j - (JW / 2 - 1);
        float u = t0 - (float)kx;
        float q = (2.0f * u) / (float)JW;
        float zz = 1.0f - q * q;
        wx[j] = (zz > 0.f) ? i0f_dev(BETA * sqrtf(zz)) : 0.f;
        int m = kx % GH; if (m < 0) m += GH;
        ix[j] = m;
    }
    #pragma unroll
    for (int j = 0; j < JW; ++j) {
        int ky = base1 + j - (JW / 2 - 1);
        float u = t1 - (float)ky;
        float q = (2.0f * u) / (float)JW;
        float zz = 1.0f - q * q;
        wy[j] = (zz > 0.f) ? i0f_dev(BETA * sqrtf(zz)) : 0.f;
        int m = ky % GW; if (m < 0) m += GW;
        iy[j] = m;
    }

    float accre = 0.f, accim = 0.f;
    #pragma unroll
    for (int a = 0; a < JW; ++a) {
        const float2* rowp = grid + ((size_t)(lb * GH + ix[a])) * GW;
        float wxa = wx[a];
        #pragma unroll
        for (int c = 0; c < JW; ++c) {
            float2 g = rowp[iy[c]];
            float w = wxa * wy[c];
            accre += w * g.x;
            accim += w * g.y;
        }
    }
    size_t p = (size_t)b * NK + k;
    if (write_complex) {
        ((float2*)out)[p] = make_float2(accre, accim);
    } else {
        out[p] = accre;
    }
}

// ---------------------------------------------------------------------------
extern "C" void kernel_launch(void* const* d_in, const int* in_sizes, int n_in,
                              void* d_out, int out_size, void* d_ws, size_t ws_size,
                              hipStream_t stream)
{
    const float* ir = (const float*)d_in[0];   // [B,640,472,1] float32
    const float* ii = (const float*)d_in[1];   // [B,640,472,1] float32
    const float* kt = (const float*)d_in[2];   // [B,2,K] float32
    float2* tw   = (float2*)d_ws;
    float2* grid = (float2*)((char*)d_ws + TW_RESERVE_BYTES);
    float*  out  = (float*)d_out;

    int write_complex = (out_size >= 2 * BATCH * NK) ? 1 : 0;

    const size_t per_batch = (size_t)GH * GW * sizeof(float2);   // 9.67 MB
    size_t avail = (ws_size > TW_RESERVE_BYTES) ? ws_size - TW_RESERVE_BYTES : 0;
    int nb = 1;
    if (avail >= 4 * per_batch)      nb = 4;
    else if (avail >= 2 * per_batch) nb = 2;

    twiddle_init_kernel<<<1, 256, 0, stream>>>(tw);

    for (int b0 = 0; b0 < BATCH; b0 += nb) {
        int total = nb * GH * GW;
        pad_apod_kernel<<<(total + 255) / 256, 256, 0, stream>>>(ir, ii, grid, b0, nb);
        fft_row_kernel<<<nb * IH, 256, 0, stream>>>(grid, tw);
        fft_col_kernel<<<nb * (GW / NC), 256, 0, stream>>>(grid, tw);
        interp_kernel<<<(nb * NK + 255) / 256, 256, 0, stream>>>(kt, grid, out, b0, nb, write_complex);
    }
}

// Round 7
// 238.971 us; speedup vs baseline: 1.8451x; 1.5477x over previous
//
#include <hip/hip_runtime.h>
#include <math.h>

// Problem constants (match reference)
#define BATCH 4
#define NK    100000
#define IH    640
#define IW    472
#define GH    1280          // oversampled grid rows = 2*IH   (1280 = 20*8*8)
#define GW    944           // oversampled grid cols = 2*IW   (944  = 59*16)
#define JW    6             // KB kernel width

// twiddle table layout in ws (units: float2): W_N^t = exp(-2*pi*i*t/N)
#define TW1280_OFF 0
#define TW944_OFF  1280
#define TW_RESERVE_BYTES 32768

#define NC      4            // columns per fft_col block
#define CSTRIDE 5            // padded LDS slot stride (float2) for fft_col buf

static __device__ __forceinline__ float beta_f() {
    return (float)(M_PI * 4.410215414239989);   // pi*sqrt(19.45)
}

// Abramowitz & Stegun I0 approximation (rel err < 2e-7), x >= 0
static __device__ __forceinline__ float i0f_dev(float x) {
    if (x < 3.75f) {
        float t = x * (1.0f / 3.75f);
        t *= t;
        return 1.0f + t*(3.5156229f + t*(3.0899424f + t*(1.2067492f +
               t*(0.2659732f + t*(0.0360768f + t*0.0045813f)))));
    } else {
        float t = 3.75f / x;
        float p = 0.39894228f + t*(0.01328592f + t*(0.00225319f + t*(-0.00157565f +
                  t*(0.00916281f + t*(-0.02057706f + t*(0.02635537f +
                  t*(-0.01647633f + t*0.00392377f)))))));
        return p * expf(x) / sqrtf(x);
    }
}

static __device__ __forceinline__ float2 cmul(float2 a, float2 b) {
    return make_float2(a.x * b.x - a.y * b.y, a.x * b.y + a.y * b.x);
}

// ---------------------------------------------------------------------------
// Kernel 0: twiddle tables
// ---------------------------------------------------------------------------
__global__ __launch_bounds__(256) void twiddle_init_kernel(float2* __restrict__ tw)
{
    int tid = threadIdx.x;
    const double TWO_PI = 6.283185307179586476925286766559;
    for (int t = tid; t < 1280; t += 256) {
        double a = -TWO_PI * ((double)t / 1280.0);
        tw[TW1280_OFF + t] = make_float2((float)cos(a), (float)sin(a));
    }
    for (int t = tid; t < 944; t += 256) {
        double a = -TWO_PI * ((double)t / 944.0);
        tw[TW944_OFF + t] = make_float2((float)cos(a), (float)sin(a));
    }
}

// ---------------------------------------------------------------------------
// Kernel 1: apodize + centered zero-pad + ifftshift + ortho scale
// Writes ONLY the 640 nonzero rows (u in [0,320) U [960,1280)); fft_col
// synthesizes the zero rows in LDS and fft_row never touches them.
// ---------------------------------------------------------------------------
__global__ __launch_bounds__(256) void pad_apod_kernel(
        const float* __restrict__ ir, const float* __restrict__ ii,
        float2* __restrict__ grid, int b0, int nb)
{
    int idx = blockIdx.x * 256 + threadIdx.x;
    if (idx >= nb * IH * GW) return;
    int v  = idx % GW;
    int t  = idx / GW;
    int ur = t % IH;                 // 0..639 enumerates nonzero rows
    int lb = t / IH;
    int b  = b0 + lb;
    int u  = (ur < (GH - IH) / 2) ? ur : ur + IH;

    int sx = u + GH / 2; if (sx >= GH) sx -= GH;
    int sy = v + GW / 2; if (sy >= GW) sy -= GW;
    int i = sx - (GH - IH) / 2;
    int j = sy - (GW - IW) / 2;

    float2 val = make_float2(0.f, 0.f);
    if ((unsigned)i < (unsigned)IH && (unsigned)j < (unsigned)IW) {
        const float B2 = (float)(M_PI * M_PI * 19.45);   // BETA^2
        float xi = (float)(i - IH / 2) * (1.0f / (float)GH);
        float yj = (float)(j - IW / 2) * (1.0f / (float)GW);
        float px = (float)(M_PI * (double)JW) * xi;
        float py = (float)(M_PI * (double)JW) * yj;
        float sxr = sqrtf(B2 - px * px);
        float syr = sqrtf(B2 - py * py);
        float ax = (float)JW * sinhf(sxr) / sxr;
        float ay = (float)JW * sinhf(syr) / syr;
        const float SCALE = (float)(1.0 / 1099.236098591787);  // 1/sqrt(1280*944)
        float invA = SCALE / (ax * ay);
        size_t src = ((size_t)(b * IH + i)) * IW + j;
        val.x = ir[src] * invA;
        val.y = ii[src] * invA;
    }
    grid[((size_t)(lb * GH + u)) * GW + v] = val;
}

// ---------------------------------------------------------------------------
// Kernel 2: length-944 row FFT (944 = 16*59), nonzero rows only.
//   u = 16*n1 + n2; k = k1 + 59*k2.
//   Z[n2*59+k1] = W944^{n2 k1} * sum_{n1 in NZ} x[16n1+n2] W59^{n1 k1}
//   X[k1+59k2]  = sum_n2 Z[n2*59+k1] W16^{n2 k2}
// Zero cols [236,708) -> stage-1 n1 runs {0..14} U {44..58} (edge groups hold
// real zeros in buf). W59 = W944^16, W16 = W944^59 — one global table.
// ---------------------------------------------------------------------------
__global__ __launch_bounds__(256) void fft_row_kernel(
        float2* __restrict__ grid, const float2* __restrict__ twg)
{
    __shared__ float2 buf[GW];            // 7552 B

    int blk = blockIdx.x;                 // nb*IH blocks
    int lb = blk / IH;
    int ri = blk % IH;
    int u  = (ri < (GH - IH) / 2) ? ri : ri + IH;
    float2* row = grid + ((size_t)(lb * GH + u)) * GW;
    int tid = threadIdx.x;
    const float2* tw = twg + TW944_OFF;

    for (int t = tid; t < GW; t += 256)
        buf[t] = (t < (GW - IW) / 2 || t >= (GW + IW) / 2) ? row[t]
                                                           : make_float2(0.f, 0.f);
    __syncthreads();

    // stage 1 -> registers
    float2 z[4];
    #pragma unroll
    for (int it = 0; it < 4; ++it) {
        int o = it * 256 + tid;
        if (o < GW) {
            int k1 = o % 59;
            int n2 = o / 59;
            float2 r = tw[16 * k1];                       // W59^{k1}
            float2 w = make_float2(1.f, 0.f);
            float re = 0.f, im = 0.f;
            for (int n1 = 0; n1 < 15; ++n1) {
                float2 x = buf[(n1 << 4) + n2];
                re += x.x * w.x - x.y * w.y;
                im += x.x * w.y + x.y * w.x;
                w = cmul(w, r);
            }
            w = tw[16 * ((44 * k1) % 59)];                // W59^{44 k1}
            for (int n1 = 44; n1 < 59; ++n1) {
                float2 x = buf[(n1 << 4) + n2];
                re += x.x * w.x - x.y * w.y;
                im += x.x * w.y + x.y * w.x;
                w = cmul(w, r);
            }
            float2 tp = tw[n2 * k1];                      // n2*k1 <= 870
            z[it] = make_float2(re * tp.x - im * tp.y, re * tp.y + im * tp.x);
        }
    }
    __syncthreads();
    #pragma unroll
    for (int it = 0; it < 4; ++it) {
        int o = it * 256 + tid;
        if (o < GW) buf[o] = z[it];
    }
    __syncthreads();

    // stage 2 -> global
    #pragma unroll
    for (int it = 0; it < 4; ++it) {
        int o = it * 256 + tid;
        if (o < GW) {
            int k1 = o % 59;
            int k2 = o / 59;
            float2 r = tw[59 * k2];                       // W16^{k2}
            float2 w = make_float2(1.f, 0.f);
            float re = 0.f, im = 0.f;
            for (int n2 = 0; n2 < 16; ++n2) {
                float2 x = buf[n2 * 59 + k1];
                re += x.x * w.x - x.y * w.y;
                im += x.x * w.y + x.y * w.x;
                w = cmul(w, r);
            }
            row[o] = make_float2(re, im);
        }
    }
}

// ---------------------------------------------------------------------------
// Kernel 3: length-1280 column FFT, 3-stage DIT 1280 = 20*8*8, 4 cols/block.
//   n = 64*n1 + m;  k = k1 + 20*k21 + 160*k22   (k1<20, k21<8, k22<8)
//   A'[k1,m]      = W1280^{m k1} * sum_{n1 in {0..4,15..19}} x[64n1+m] W20^{n1 k1}
//   C [k1,k21,m2] = W64^{m2 k21} * sum_{m1<8} A'[k1,8m1+m2] W8^{m1 k21}
//   X [k]         = sum_{m2<8} C[k1,k21,m2] W8^{m2 k22}
// Zero rows [320,960) = n1 in [5,15): skipped in stage A AND never fetched.
// All stage reads are broadcast-form (lane index only in output slot).
// W20 = W1280^64, W64 = W1280^20, W8 = W1280^160.
// ---------------------------------------------------------------------------
__global__ __launch_bounds__(256) void fft_col_kernel(
        float2* __restrict__ grid, const float2* __restrict__ twg)
{
    __shared__ float2 buf[GH * CSTRIDE];   // 51200 B -> 3 blocks/CU

    int blk = blockIdx.x;                  // nb * 236
    int lb = blk / (GW / NC);
    int vb = blk % (GW / NC);
    float2* base = grid + (size_t)lb * GH * GW + vb * NC;
    int tid = threadIdx.x;
    const float2* tw = twg + TW1280_OFF;

    // load (nonzero rows only; zero-fill the pad band)
    #pragma unroll
    for (int it = 0; it < 20; ++it) {
        int item = it * 256 + tid;
        int c = item & (NC - 1);
        int u = item >> 2;
        float2 v = make_float2(0.f, 0.f);
        if (u < 320 || u >= 960) v = base[(size_t)u * GW + c];
        buf[u * CSTRIDE + c] = v;
    }
    __syncthreads();

    float2 z[20];

    // ---- stage A: radix-20 with zero-skip; slot o = m*20 + k1
    #pragma unroll
    for (int it = 0; it < 20; ++it) {
        int item = it * 256 + tid;
        int c = item & 3;
        int o = item >> 2;
        int k1 = o % 20;
        int m  = o / 20;
        float2 r = tw[64 * k1];                           // W20^{k1}
        float2 w = make_float2(1.f, 0.f);
        float re = 0.f, im = 0.f;
        for (int n1 = 0; n1 < 5; ++n1) {
            float2 x = buf[((n1 << 6) + m) * CSTRIDE + c];
            re += x.x * w.x - x.y * w.y;
            im += x.x * w.y + x.y * w.x;
            w = cmul(w, r);
        }
        w = tw[64 * ((15 * k1) % 20)];                    // W20^{15 k1}
        for (int n1 = 15; n1 < 20; ++n1) {
            float2 x = buf[((n1 << 6) + m) * CSTRIDE + c];
            re += x.x * w.x - x.y * w.y;
            im += x.x * w.y + x.y * w.x;
            w = cmul(w, r);
        }
        float2 tp = tw[m * k1];                           // m*k1 <= 1197
        z[it] = make_float2(re * tp.x - im * tp.y, re * tp.y + im * tp.x);
    }
    __syncthreads();
    #pragma unroll
    for (int it = 0; it < 20; ++it) {
        int item = it * 256 + tid;
        buf[(item >> 2) * CSTRIDE + (item & 3)] = z[it];
    }
    __syncthreads();

    // ---- stage B: radix-8 over m1; read slot (8m1+m2)*20+k1, out slot o2
    #pragma unroll
    for (int it = 0; it < 20; ++it) {
        int item = it * 256 + tid;
        int c   = item & 3;
        int o2  = item >> 2;
        int k21 = o2 & 7;
        int t2  = o2 >> 3;           // = m2*20 + k1
        int k1  = t2 % 20;
        int m2  = t2 / 20;
        float2 r = tw[160 * k21];                         // W8^{k21}
        float2 w = make_float2(1.f, 0.f);
        float re = 0.f, im = 0.f;
        for (int m1 = 0; m1 < 8; ++m1) {
            float2 x = buf[(((m1 << 3) + m2) * 20 + k1) * CSTRIDE + c];
            re += x.x * w.x - x.y * w.y;
            im += x.x * w.y + x.y * w.x;
            w = cmul(w, r);
        }
        float2 tp = tw[20 * m2 * k21];                    // W64^{m2 k21}
        z[it] = make_float2(re * tp.x - im * tp.y, re * tp.y + im * tp.x);
    }
    __syncthreads();
    #pragma unroll
    for (int it = 0; it < 20; ++it) {
        int item = it * 256 + tid;
        buf[(item >> 2) * CSTRIDE + (item & 3)] = z[it];
    }
    __syncthreads();

    // ---- stage C: radix-8 over m2; read slot (m2*20+k1)*8+k21 -> global
    #pragma unroll
    for (int it = 0; it < 20; ++it) {
        int item = it * 256 + tid;
        int c   = item & 3;
        int o3  = item >> 2;
        int k22 = o3 & 7;
        int t3  = o3 >> 3;           // = k1*8 + k21
        int k21 = t3 & 7;
        int k1  = t3 >> 3;
        float2 r = tw[160 * k22];                         // W8^{k22}
        float2 w = make_float2(1.f, 0.f);
        float re = 0.f, im = 0.f;
        for (int m2 = 0; m2 < 8; ++m2) {
            float2 x = buf[((m2 * 20 + k1) * 8 + k21) * CSTRIDE + c];
            re += x.x * w.x - x.y * w.y;
            im += x.x * w.y + x.y * w.x;
            w = cmul(w, r);
        }
        int rrow = k1 + 20 * k21 + 160 * k22;
        base[(size_t)rrow * GW + c] = make_float2(re, im);
    }
}

// ---------------------------------------------------------------------------
// Kernel 4: KB interpolation onto non-uniform points
// ---------------------------------------------------------------------------
__global__ __launch_bounds__(256) void interp_kernel(
        const float* __restrict__ ktraj, const float2* __restrict__ grid,
        float* __restrict__ out, int b0, int nb, int write_complex)
{
    int idx = blockIdx.x * 256 + threadIdx.x;
    if (idx >= nb * NK) return;
    int lb = idx / NK;
    int k  = idx % NK;
    int b  = b0 + lb;

    const float BETA = beta_f();
    float t0 = ktraj[(size_t)(b * 2 + 0) * NK + k] * (float)((double)GH / (2.0 * M_PI));
    float t1 = ktraj[(size_t)(b * 2 + 1) * NK + k] * (float)((double)GW / (2.0 * M_PI));
    int base0 = (int)floorf(t0);
    int base1 = (int)floorf(t1);

    float wx[JW], wy[JW];
    int   ix[JW], iy[JW];
    #pragma unroll
    for (int j = 0; j < JW; ++j) {
        int kx = base0 + j - (JW / 2 - 1);
        float u = t0 - (float)kx;
        float q = (2.0f * u) / (float)JW;
        float zz = 1.0f - q * q;
        wx[j] = (zz > 0.f) ? i0f_dev(BETA * sqrtf(zz)) : 0.f;
        int m = kx % GH; if (m < 0) m += GH;
        ix[j] = m;
    }
    #pragma unroll
    for (int j = 0; j < JW; ++j) {
        int ky = base1 + j - (JW / 2 - 1);
        float u = t1 - (float)ky;
        float q = (2.0f * u) / (float)JW;
        float zz = 1.0f - q * q;
        wy[j] = (zz > 0.f) ? i0f_dev(BETA * sqrtf(zz)) : 0.f;
        int m = ky % GW; if (m < 0) m += GW;
        iy[j] = m;
    }

    float accre = 0.f, accim = 0.f;
    #pragma unroll
    for (int a = 0; a < JW; ++a) {
        const float2* rowp = grid + ((size_t)(lb * GH + ix[a])) * GW;
        float wxa = wx[a];
        #pragma unroll
        for (int c = 0; c < JW; ++c) {
            float2 g = rowp[iy[c]];
            float w = wxa * wy[c];
            accre += w * g.x;
            accim += w * g.y;
        }
    }
    size_t p = (size_t)b * NK + k;
    if (write_complex) {
        ((float2*)out)[p] = make_float2(accre, accim);
    } else {
        out[p] = accre;
    }
}

// ---------------------------------------------------------------------------
extern "C" void kernel_launch(void* const* d_in, const int* in_sizes, int n_in,
                              void* d_out, int out_size, void* d_ws, size_t ws_size,
                              hipStream_t stream)
{
    const float* ir = (const float*)d_in[0];   // [B,640,472,1] float32
    const float* ii = (const float*)d_in[1];   // [B,640,472,1] float32
    const float* kt = (const float*)d_in[2];   // [B,2,K] float32
    float2* tw   = (float2*)d_ws;
    float2* grid = (float2*)((char*)d_ws + TW_RESERVE_BYTES);
    float*  out  = (float*)d_out;

    int write_complex = (out_size >= 2 * BATCH * NK) ? 1 : 0;

    const size_t per_batch = (size_t)GH * GW * sizeof(float2);   // 9.67 MB
    size_t avail = (ws_size > TW_RESERVE_BYTES) ? ws_size - TW_RESERVE_BYTES : 0;
    int nb = 1;
    if (avail >= 4 * per_batch)      nb = 4;
    else if (avail >= 2 * per_batch) nb = 2;

    twiddle_init_kernel<<<1, 256, 0, stream>>>(tw);

    for (int b0 = 0; b0 < BATCH; b0 += nb) {
        int total = nb * IH * GW;
        pad_apod_kernel<<<(total + 255) / 256, 256, 0, stream>>>(ir, ii, grid, b0, nb);
        fft_row_kernel<<<nb * IH, 256, 0, stream>>>(grid, tw);
        fft_col_kernel<<<nb * (GW / NC), 256, 0, stream>>>(grid, tw);
        interp_kernel<<<(nb * NK + 255) / 256, 256, 0, stream>>>(kt, grid, out, b0, nb, write_complex);
    }
}

// Round 8
// 203.545 us; speedup vs baseline: 2.1663x; 1.1740x over previous
//
#include <hip/hip_runtime.h>
#include <math.h>

// Problem constants (match reference)
#define BATCH 4
#define NK    100000
#define IH    640
#define IW    472
#define GH    1280          // oversampled grid rows = 2*IH   (1280 = 20*8*8)
#define GW    944           // oversampled grid cols = 2*IW   (944  = 59*16)
#define GWP   952           // padded row stride: 8 echo cols for wrap-free float4 windows
#define JW    6             // KB kernel width

// twiddle table layout in ws (units: float2): W_N^t = exp(-2*pi*i*t/N)
#define TW1280_OFF 0
#define TW944_OFF  1280
#define TW_RESERVE_BYTES 32768

#define NC      4            // columns per fft_col block
#define CSTRIDE 5            // padded LDS slot stride (float2) for fft_col buf

static __device__ __forceinline__ float beta_f() {
    return (float)(M_PI * 4.410215414239989);   // pi*sqrt(19.45)
}

// Abramowitz & Stegun I0 approximation (rel err < 2e-7), x >= 0
static __device__ __forceinline__ float i0f_dev(float x) {
    if (x < 3.75f) {
        float t = x * (1.0f / 3.75f);
        t *= t;
        return 1.0f + t*(3.5156229f + t*(3.0899424f + t*(1.2067492f +
               t*(0.2659732f + t*(0.0360768f + t*0.0045813f)))));
    } else {
        float t = 3.75f / x;
        float p = 0.39894228f + t*(0.01328592f + t*(0.00225319f + t*(-0.00157565f +
                  t*(0.00916281f + t*(-0.02057706f + t*(0.02635537f +
                  t*(-0.01647633f + t*0.00392377f)))))));
        return p * expf(x) / sqrtf(x);
    }
}

static __device__ __forceinline__ float2 cmul(float2 a, float2 b) {
    return make_float2(a.x * b.x - a.y * b.y, a.x * b.y + a.y * b.x);
}

// ---------------------------------------------------------------------------
// Kernel 0: twiddle tables (5 blocks)
// ---------------------------------------------------------------------------
__global__ __launch_bounds__(256) void twiddle_init_kernel(float2* __restrict__ tw)
{
    int idx = blockIdx.x * 256 + threadIdx.x;
    const double TWO_PI = 6.283185307179586476925286766559;
    if (idx < 1280) {
        double a = -TWO_PI * ((double)idx / 1280.0);
        tw[TW1280_OFF + idx] = make_float2((float)cos(a), (float)sin(a));
    }
    if (idx < 944) {
        double a = -TWO_PI * ((double)idx / 944.0);
        tw[TW944_OFF + idx] = make_float2((float)cos(a), (float)sin(a));
    }
}

// ---------------------------------------------------------------------------
// Kernel 1: FUSED apodize+pad+ifftshift+scale + length-944 row FFT.
// One block per nonzero output row u (u<320: img row i=u+320; u>=960: i=u-960... 
// enumerated by ri: u = ri<320 ? ri : ri+640,  i = ri<320 ? ri+320 : ri-320).
// Nonzero cols: t<236 -> img col j=t+236; t>=708 -> j=t-708; else zero.
//   944 = 16*59 DIT: u=16n1+n2, k=k1+59k2
//   Z[n2*59+k1] = W944^{n2 k1} * sum_{n1 in {0..14,44..58}} x[16n1+n2] W59^{n1 k1}
//   X[k1+59k2]  = sum_n2 Z[n2*59+k1] W16^{n2 k2}
// ---------------------------------------------------------------------------
__global__ __launch_bounds__(256) void fft_row_kernel(
        const float* __restrict__ ir, const float* __restrict__ ii,
        float2* __restrict__ grid, const float2* __restrict__ twg,
        int b0, int nb)
{
    __shared__ float2 buf[GW];            // 7552 B

    int blk = blockIdx.x;                 // nb*IH blocks
    int lb = blk / IH;
    int ri = blk % IH;
    int b  = b0 + lb;
    int u  = (ri < 320) ? ri : ri + 640;
    int i  = (ri < 320) ? ri + 320 : ri - 320;
    float2* row = grid + ((size_t)(lb * GH + u)) * GWP;
    int tid = threadIdx.x;
    const float2* tw = twg + TW944_OFF;

    // row-constant apodization factor ax(i)
    const float B2 = (float)(M_PI * M_PI * 19.45);   // BETA^2
    float xi = (float)(i - IH / 2) * (1.0f / (float)GH);
    float px = (float)(M_PI * (double)JW) * xi;
    float sxr = sqrtf(B2 - px * px);
    float ax = (float)JW * sinhf(sxr) / sxr;
    const float SCALE = (float)(1.0 / 1099.236098591787);  // 1/sqrt(1280*944)
    float rowscale = SCALE / ax;
    const float* irow = ir + (size_t)(b * IH + i) * IW;
    const float* iirow = ii + (size_t)(b * IH + i) * IW;

    for (int t = tid; t < GW; t += 256) {
        float2 val = make_float2(0.f, 0.f);
        int j = -1;
        if (t < (GW - IW) / 2) j = t + IW / 2;           // 236..471
        else if (t >= (GW + IW) / 2) j = t - (GW + IW) / 2;  // 0..235
        if (j >= 0) {
            float yj = (float)(j - IW / 2) * (1.0f / (float)GW);
            float py = (float)(M_PI * (double)JW) * yj;
            float syr = sqrtf(B2 - py * py);
            float ay = (float)JW * sinhf(syr) / syr;
            float invA = rowscale / ay;
            val.x = irow[j] * invA;
            val.y = iirow[j] * invA;
        }
        buf[t] = val;
    }
    __syncthreads();

    // stage 1 -> registers
    float2 z[4];
    #pragma unroll
    for (int it = 0; it < 4; ++it) {
        int o = it * 256 + tid;
        if (o < GW) {
            int k1 = o % 59;
            int n2 = o / 59;
            float2 r = tw[16 * k1];                       // W59^{k1}
            float2 w = make_float2(1.f, 0.f);
            float re = 0.f, im = 0.f;
            for (int n1 = 0; n1 < 15; ++n1) {
                float2 x = buf[(n1 << 4) + n2];
                re += x.x * w.x - x.y * w.y;
                im += x.x * w.y + x.y * w.x;
                w = cmul(w, r);
            }
            w = tw[16 * ((44 * k1) % 59)];                // W59^{44 k1}
            for (int n1 = 44; n1 < 59; ++n1) {
                float2 x = buf[(n1 << 4) + n2];
                re += x.x * w.x - x.y * w.y;
                im += x.x * w.y + x.y * w.x;
                w = cmul(w, r);
            }
            float2 tp = tw[n2 * k1];                      // n2*k1 <= 870
            z[it] = make_float2(re * tp.x - im * tp.y, re * tp.y + im * tp.x);
        }
    }
    __syncthreads();
    #pragma unroll
    for (int it = 0; it < 4; ++it) {
        int o = it * 256 + tid;
        if (o < GW) buf[o] = z[it];
    }
    __syncthreads();

    // stage 2 -> global
    #pragma unroll
    for (int it = 0; it < 4; ++it) {
        int o = it * 256 + tid;
        if (o < GW) {
            int k1 = o % 59;
            int k2 = o / 59;
            float2 r = tw[59 * k2];                       // W16^{k2}
            float2 w = make_float2(1.f, 0.f);
            float re = 0.f, im = 0.f;
            for (int n2 = 0; n2 < 16; ++n2) {
                float2 x = buf[n2 * 59 + k1];
                re += x.x * w.x - x.y * w.y;
                im += x.x * w.y + x.y * w.x;
                w = cmul(w, r);
            }
            row[o] = make_float2(re, im);
        }
    }
}

// ---------------------------------------------------------------------------
// Kernel 2: length-1280 column FFT, 3-stage DIT 1280 = 20*8*8, 4 cols/block.
// Zero rows [320,960) skipped in stage A and never fetched.
// ---------------------------------------------------------------------------
__global__ __launch_bounds__(256) void fft_col_kernel(
        float2* __restrict__ grid, const float2* __restrict__ twg)
{
    __shared__ float2 buf[GH * CSTRIDE];   // 51200 B

    int blk = blockIdx.x;                  // nb * 236
    int lb = blk / (GW / NC);
    int vb = blk % (GW / NC);
    float2* base = grid + (size_t)lb * GH * GWP + vb * NC;
    int tid = threadIdx.x;
    const float2* tw = twg + TW1280_OFF;

    // load (nonzero rows only; zero-fill the pad band)
    #pragma unroll
    for (int it = 0; it < 20; ++it) {
        int item = it * 256 + tid;
        int c = item & (NC - 1);
        int u = item >> 2;
        float2 v = make_float2(0.f, 0.f);
        if (u < 320 || u >= 960) v = base[(size_t)u * GWP + c];
        buf[u * CSTRIDE + c] = v;
    }
    __syncthreads();

    float2 z[20];

    // ---- stage A: radix-20 with zero-skip; slot o = m*20 + k1
    #pragma unroll
    for (int it = 0; it < 20; ++it) {
        int item = it * 256 + tid;
        int c = item & 3;
        int o = item >> 2;
        int k1 = o % 20;
        int m  = o / 20;
        float2 r = tw[64 * k1];                           // W20^{k1}
        float2 w = make_float2(1.f, 0.f);
        float re = 0.f, im = 0.f;
        for (int n1 = 0; n1 < 5; ++n1) {
            float2 x = buf[((n1 << 6) + m) * CSTRIDE + c];
            re += x.x * w.x - x.y * w.y;
            im += x.x * w.y + x.y * w.x;
            w = cmul(w, r);
        }
        w = tw[64 * ((15 * k1) % 20)];                    // W20^{15 k1}
        for (int n1 = 15; n1 < 20; ++n1) {
            float2 x = buf[((n1 << 6) + m) * CSTRIDE + c];
            re += x.x * w.x - x.y * w.y;
            im += x.x * w.y + x.y * w.x;
            w = cmul(w, r);
        }
        float2 tp = tw[m * k1];
        z[it] = make_float2(re * tp.x - im * tp.y, re * tp.y + im * tp.x);
    }
    __syncthreads();
    #pragma unroll
    for (int it = 0; it < 20; ++it) {
        int item = it * 256 + tid;
        buf[(item >> 2) * CSTRIDE + (item & 3)] = z[it];
    }
    __syncthreads();

    // ---- stage B: radix-8 over m1
    #pragma unroll
    for (int it = 0; it < 20; ++it) {
        int item = it * 256 + tid;
        int c   = item & 3;
        int o2  = item >> 2;
        int k21 = o2 & 7;
        int t2  = o2 >> 3;           // = m2*20 + k1
        int k1  = t2 % 20;
        int m2  = t2 / 20;
        float2 r = tw[160 * k21];                         // W8^{k21}
        float2 w = make_float2(1.f, 0.f);
        float re = 0.f, im = 0.f;
        for (int m1 = 0; m1 < 8; ++m1) {
            float2 x = buf[(((m1 << 3) + m2) * 20 + k1) * CSTRIDE + c];
            re += x.x * w.x - x.y * w.y;
            im += x.x * w.y + x.y * w.x;
            w = cmul(w, r);
        }
        float2 tp = tw[20 * m2 * k21];                    // W64^{m2 k21}
        z[it] = make_float2(re * tp.x - im * tp.y, re * tp.y + im * tp.x);
    }
    __syncthreads();
    #pragma unroll
    for (int it = 0; it < 20; ++it) {
        int item = it * 256 + tid;
        buf[(item >> 2) * CSTRIDE + (item & 3)] = z[it];
    }
    __syncthreads();

    // ---- stage C: radix-8 over m2 -> global
    #pragma unroll
    for (int it = 0; it < 20; ++it) {
        int item = it * 256 + tid;
        int c   = item & 3;
        int o3  = item >> 2;
        int k22 = o3 & 7;
        int t3  = o3 >> 3;           // = k1*8 + k21
        int k21 = t3 & 7;
        int k1  = t3 >> 3;
        float2 r = tw[160 * k22];                         // W8^{k22}
        float2 w = make_float2(1.f, 0.f);
        float re = 0.f, im = 0.f;
        for (int m2 = 0; m2 < 8; ++m2) {
            float2 x = buf[((m2 * 20 + k1) * 8 + k21) * CSTRIDE + c];
            re += x.x * w.x - x.y * w.y;
            im += x.x * w.y + x.y * w.x;
            w = cmul(w, r);
        }
        int rrow = k1 + 20 * k21 + 160 * k22;
        base[(size_t)rrow * GWP + c] = make_float2(re, im);
    }
}

// ---------------------------------------------------------------------------
// Kernel 3: echo cols 0..7 into the pad band [944,952) so interp's 8-tap
// float4 windows never wrap in y.
// ---------------------------------------------------------------------------
__global__ __launch_bounds__(256) void wrap_cols_kernel(float2* __restrict__ grid, int nb)
{
    int idx = blockIdx.x * 256 + threadIdx.x;
    if (idx >= nb * GH * 8) return;
    int c  = idx & 7;
    int t  = idx >> 3;
    int u  = t % GH;
    int lb = t / GH;
    float2* row = grid + ((size_t)(lb * GH + u)) * GWP;
    row[GW + c] = row[c];
}

// ---------------------------------------------------------------------------
// Kernel 4: KB interpolation. Y-taps read as 4 aligned float4 (8-tap window,
// extra taps get zero KB weight); X-taps are 6 individually wrapped rows.
// ---------------------------------------------------------------------------
__global__ __launch_bounds__(256) void interp_kernel(
        const float* __restrict__ ktraj, const float2* __restrict__ grid,
        float* __restrict__ out, int b0, int nb, int write_complex)
{
    int idx = blockIdx.x * 256 + threadIdx.x;
    if (idx >= nb * NK) return;
    int lb = idx / NK;
    int k  = idx % NK;
    int b  = b0 + lb;

    const float BETA = beta_f();
    float t0 = ktraj[(size_t)(b * 2 + 0) * NK + k] * (float)((double)GH / (2.0 * M_PI));
    float t1 = ktraj[(size_t)(b * 2 + 1) * NK + k] * (float)((double)GW / (2.0 * M_PI));
    int base0 = (int)floorf(t0);
    int base1 = (int)floorf(t1);

    // x: 6 wrapped rows + weights
    float wx[JW];
    int   ix[JW];
    #pragma unroll
    for (int j = 0; j < JW; ++j) {
        int kx = base0 + j - (JW / 2 - 1);
        float u = t0 - (float)kx;
        float q = u * (1.0f / 3.0f);
        float zz = 1.0f - q * q;
        wx[j] = (zz > 0.f) ? i0f_dev(BETA * sqrtf(zz)) : 0.f;
        int m = kx % GH; if (m < 0) m += GH;
        ix[j] = m;
    }

    // y: even-aligned 8-tap window [a0u, a0u+8); taps outside |u|<3 get w=0
    int j0u = base1 - 2;
    int a0u = j0u - (j0u & 1);          // even (two's complement ok for negatives)
    int aw  = a0u; if (aw < 0) aw += GW;  // in [0,942], even -> 16B-aligned
    float wy8[8];
    #pragma unroll
    for (int t = 0; t < 8; ++t) {
        float u = t1 - (float)(a0u + t);
        float q = u * (1.0f / 3.0f);
        float zz = 1.0f - q * q;
        wy8[t] = (zz > 0.f) ? i0f_dev(BETA * sqrtf(zz)) : 0.f;
    }

    float accre = 0.f, accim = 0.f;
    #pragma unroll
    for (int a = 0; a < JW; ++a) {
        const float4* p4 = (const float4*)(grid + ((size_t)(lb * GH + ix[a])) * GWP + aw);
        float4 v0 = p4[0];
        float4 v1 = p4[1];
        float4 v2 = p4[2];
        float4 v3 = p4[3];
        float rre = wy8[0]*v0.x + wy8[1]*v0.z + wy8[2]*v1.x + wy8[3]*v1.z
                  + wy8[4]*v2.x + wy8[5]*v2.z + wy8[6]*v3.x + wy8[7]*v3.z;
        float rim = wy8[0]*v0.y + wy8[1]*v0.w + wy8[2]*v1.y + wy8[3]*v1.w
                  + wy8[4]*v2.y + wy8[5]*v2.w + wy8[6]*v3.y + wy8[7]*v3.w;
        accre += wx[a] * rre;
        accim += wx[a] * rim;
    }
    size_t p = (size_t)b * NK + k;
    if (write_complex) {
        ((float2*)out)[p] = make_float2(accre, accim);
    } else {
        out[p] = accre;
    }
}

// ---------------------------------------------------------------------------
extern "C" void kernel_launch(void* const* d_in, const int* in_sizes, int n_in,
                              void* d_out, int out_size, void* d_ws, size_t ws_size,
                              hipStream_t stream)
{
    const float* ir = (const float*)d_in[0];   // [B,640,472,1] float32
    const float* ii = (const float*)d_in[1];   // [B,640,472,1] float32
    const float* kt = (const float*)d_in[2];   // [B,2,K] float32
    float2* tw   = (float2*)d_ws;
    float2* grid = (float2*)((char*)d_ws + TW_RESERVE_BYTES);
    float*  out  = (float*)d_out;

    int write_complex = (out_size >= 2 * BATCH * NK) ? 1 : 0;

    const size_t per_batch = (size_t)GH * GWP * sizeof(float2);  // 9.75 MB
    size_t avail = (ws_size > TW_RESERVE_BYTES) ? ws_size - TW_RESERVE_BYTES : 0;
    int nb = 1;
    if (avail >= 4 * per_batch)      nb = 4;
    else if (avail >= 2 * per_batch) nb = 2;

    twiddle_init_kernel<<<5, 256, 0, stream>>>(tw);

    for (int b0 = 0; b0 < BATCH; b0 += nb) {
        fft_row_kernel<<<nb * IH, 256, 0, stream>>>(ir, ii, grid, tw, b0, nb);
        fft_col_kernel<<<nb * (GW / NC), 256, 0, stream>>>(grid, tw);
        wrap_cols_kernel<<<(nb * GH * 8 + 255) / 256, 256, 0, stream>>>(grid, nb);
        interp_kernel<<<(nb * NK + 255) / 256, 256, 0, stream>>>(kt, grid, out, b0, nb, write_complex);
    }
}